// Round 6
// baseline (368.982 us; speedup 1.0000x reference)
//
#include <hip/hip_runtime.h>
#include <stdint.h>

// Problem constants
#define BB 16384
#define DD 1024
#define HH 1024
#define OO 256
#define CC 8

typedef unsigned short u16;
typedef __attribute__((ext_vector_type(4))) unsigned short u16x4;
typedef __attribute__((ext_vector_type(8))) short bf16x8;
typedef __attribute__((ext_vector_type(4))) float f32x4;

__device__ __forceinline__ u16 f2bf(float f) {
    union { float f; uint32_t u; } v; v.f = f;
    const uint32_t u = v.u;
    return (u16)((u + 0x7FFFu + ((u >> 16) & 1u)) >> 16);  // RNE
}

// async global->LDS, 16B per lane (dest must be wave-uniform base + lane*16)
#define GLDS16(g, l)                                                                   \
    __builtin_amdgcn_global_load_lds((const __attribute__((address_space(1))) void*)(g), \
                                     (__attribute__((address_space(3))) void*)(l), 16, 0, 0)

// ---------------------------------------------------------------------------
// Transpose fp32 [nmat][R][Cc] -> bf16 [nmat][Cc][R]  (W -> W^T, K-contiguous)
// ---------------------------------------------------------------------------
__global__ __launch_bounds__(256)
void transpose_bf16_kernel(const float* __restrict__ src, u16* __restrict__ dst,
                           int R, int Cc)
{
    __shared__ float t[32][33];
    const int tid = threadIdx.x;
    const int mat = blockIdx.z;
    const int r0 = blockIdx.y * 32, c0 = blockIdx.x * 32;
    {
        const int rr = tid >> 3, c4 = (tid & 7) * 4;
        const float4 v = *(const float4*)(src + ((size_t)mat * R + r0 + rr) * Cc + c0 + c4);
        t[rr][c4 + 0] = v.x; t[rr][c4 + 1] = v.y; t[rr][c4 + 2] = v.z; t[rr][c4 + 3] = v.w;
    }
    __syncthreads();
    {
        const int cc = tid >> 3, k4 = (tid & 7) * 4;
        u16x4 o;
        o[0] = f2bf(t[k4 + 0][cc]);
        o[1] = f2bf(t[k4 + 1][cc]);
        o[2] = f2bf(t[k4 + 2][cc]);
        o[3] = f2bf(t[k4 + 3][cc]);
        *(u16x4*)(dst + ((size_t)mat * Cc + c0 + cc) * R + r0 + k4) = o;
    }
}

// ---------------------------------------------------------------------------
// Logits (fp32, exact routing) + x -> bf16 + per-block class histogram.
// ---------------------------------------------------------------------------
__global__ __launch_bounds__(256)
void logits_kernel(const float* __restrict__ x, const float* __restrict__ Wc,
                   const float* __restrict__ bc, float* __restrict__ logits_out,
                   u16* __restrict__ x_bf16, int* __restrict__ class_idx,
                   int* __restrict__ hist)
{
    __shared__ float WcT[CC][DD];  // 32 KB, transposed classifier
    __shared__ int clsarr[16];
    const int tid = threadIdx.x;
    #pragma unroll
    for (int j = 0; j < 8; ++j) {
        const int f = tid + 256 * j;                 // float4 index into Wc [D][C]
        const float4 v = ((const float4*)Wc)[f];
        const int d = f >> 1, c = (f & 1) * 4;       // 4 elems share d (C=8)
        WcT[c + 0][d] = v.x; WcT[c + 1][d] = v.y; WcT[c + 2][d] = v.z; WcT[c + 3][d] = v.w;
    }
    __syncthreads();

    const int lane = tid & 63, wv = tid >> 6;
    const int row0 = blockIdx.x * 16 + wv * 4;

    float acc[4][8];
    #pragma unroll
    for (int r = 0; r < 4; ++r)
        #pragma unroll
        for (int c = 0; c < 8; ++c) acc[r][c] = 0.f;

    #pragma unroll
    for (int p = 0; p < 2; ++p) {
        float4 xv[2][4];
        #pragma unroll
        for (int rr = 0; rr < 2; ++rr) {
            const float4* xr = (const float4*)(x + (size_t)(row0 + 2 * p + rr) * DD);
            #pragma unroll
            for (int j = 0; j < 4; ++j) xv[rr][j] = xr[lane + 64 * j];
        }
        #pragma unroll
        for (int rr = 0; rr < 2; ++rr) {
            u16* xb = x_bf16 + (size_t)(row0 + 2 * p + rr) * DD;
            #pragma unroll
            for (int j = 0; j < 4; ++j) {
                const float4 v = xv[rr][j];
                u16x4 o; o[0] = f2bf(v.x); o[1] = f2bf(v.y); o[2] = f2bf(v.z); o[3] = f2bf(v.w);
                *(u16x4*)(xb + 4 * (lane + 64 * j)) = o;
            }
        }
        #pragma unroll
        for (int j = 0; j < 4; ++j) {
            const int f = lane + 64 * j;
            #pragma unroll
            for (int c = 0; c < 8; ++c) {
                const float4 w = *(const float4*)&WcT[c][4 * f];
                #pragma unroll
                for (int rr = 0; rr < 2; ++rr)
                    acc[2 * p + rr][c] += xv[rr][j].x * w.x + xv[rr][j].y * w.y
                                        + xv[rr][j].z * w.z + xv[rr][j].w * w.w;
            }
        }
    }

    #pragma unroll
    for (int off = 8; off < 64; off <<= 1)
        #pragma unroll
        for (int r = 0; r < 4; ++r)
            #pragma unroll
            for (int c = 0; c < 8; ++c)
                acc[r][c] += __shfl_xor(acc[r][c], off, 64);

    const int cls = lane >> 3;
    const float bcv = bc[cls];
    float s[4];
    #pragma unroll
    for (int r = 0; r < 4; ++r) {
        float v = acc[r][0];
        #pragma unroll
        for (int c = 1; c < 8; ++c) v = (cls == c) ? acc[r][c] : v;
        s[r] = v;
    }
    #pragma unroll
    for (int off = 1; off < 8; off <<= 1)
        #pragma unroll
        for (int r = 0; r < 4; ++r) s[r] += __shfl_xor(s[r], off, 64);
    #pragma unroll
    for (int r = 0; r < 4; ++r) s[r] += bcv;

    #pragma unroll
    for (int r = 0; r < 4; ++r)
        if ((lane & 7) == 0) logits_out[(size_t)(row0 + r) * CC + cls] = s[r];

    int idx[4] = {cls, cls, cls, cls};
    #pragma unroll
    for (int off = 8; off < 64; off <<= 1) {
        #pragma unroll
        for (int r = 0; r < 4; ++r) {
            const float ov = __shfl_xor(s[r], off, 64);
            const int oi = __shfl_xor(idx[r], off, 64);
            const bool take = (ov > s[r]) || (ov == s[r] && oi < idx[r]);
            s[r] = take ? ov : s[r];
            idx[r] = take ? oi : idx[r];
        }
    }
    if (lane == 0) {
        #pragma unroll
        for (int r = 0; r < 4; ++r) {
            class_idx[row0 + r] = idx[r];
            clsarr[wv * 4 + r] = idx[r];
        }
    }
    __syncthreads();
    if (tid < 64) {
        const int myc = (tid < 16) ? clsarr[tid] : -1;
        int h = 0;
        #pragma unroll
        for (int cc = 0; cc < 8; ++cc) {
            const int p = __popcll(__ballot(myc == cc));
            h = (tid == cc) ? p : h;
        }
        if (tid < 8) hist[blockIdx.x * 8 + tid] = h;
    }
}

// ---------------------------------------------------------------------------
// Single-block scan: per-class totals -> padded offsets (256-granular) +
// per-block scatter bases.
// ---------------------------------------------------------------------------
__global__ __launch_bounds__(256)
void scan_kernel(const int* __restrict__ hist, int* __restrict__ offsets,
                 int* __restrict__ bb)
{
    const int t = threadIdx.x, c = t >> 5, g = t & 31;
    int sum = 0;
    #pragma unroll 4
    for (int i = 0; i < 32; ++i) sum += hist[(g * 32 + i) * 8 + c];
    int inc = sum;
    #pragma unroll
    for (int d = 1; d < 32; d <<= 1) {
        const int v = __shfl_up(inc, d, 32);
        if (g >= d) inc += v;
    }
    __shared__ int tot[8], offL[9];
    if (g == 31) tot[c] = inc;
    __syncthreads();
    if (t == 0) {
        int o = 0; offL[0] = 0; offsets[0] = 0;
        #pragma unroll
        for (int c8 = 0; c8 < 8; ++c8) {
            o += (tot[c8] + 255) & ~255;          // pad to 256 (BM of layer GEMMs)
            offL[c8 + 1] = o; offsets[c8 + 1] = o;
        }
    }
    __syncthreads();
    int base = offL[c] + (inc - sum);
    #pragma unroll 4
    for (int i = 0; i < 32; ++i) {
        const int b = g * 32 + i;
        bb[b * 8 + c] = base;
        base += hist[b * 8 + c];
    }
}

// ---------------------------------------------------------------------------
// Scatter row ids into per-class segments — atomic-free via ballot ranking.
// ---------------------------------------------------------------------------
__global__ __launch_bounds__(256)
void scatter_kernel(const int* __restrict__ class_idx, const int* __restrict__ bb,
                    int* __restrict__ rowidx)
{
    const int r = blockIdx.x * 256 + threadIdx.x;
    const int c = class_idx[r];
    const int lane = threadIdx.x & 63;
    const int gl = lane & ~15;
    const unsigned long long before = (1ull << lane) - (1ull << gl);
    int rank = 0;
    #pragma unroll
    for (int cc = 0; cc < 8; ++cc) {
        const unsigned long long m = __ballot(c == cc);
        const int p = __popcll(m & before);
        rank = (c == cc) ? p : rank;
    }
    rowidx[bb[(r >> 4) * 8 + c] + rank] = r;
}

// ---------------------------------------------------------------------------
// R6 main GEMM (layers 1-3): BM=256, BN=128, BK=32, 256 thr / 4 waves,
// wave = 128x64 output (8 m-frags x 4 n-frags -> 0.375 KB LDS read / MFMA).
// - Wave-partitioned staging: w1/w2 stage A halves (8 glds), w0/w3 stage B
//   halves (4 glds). Per-thread own-count vmcnt (8/4, never 0 except last
//   tile) + ONE s_barrier per K-tile certifies the tile (own-wait+barrier
//   == __syncthreads semantics, without the vmcnt(0) drain).
// - 3 LDS buffers (72 KB -> 2 blocks/CU): stage(t+1) at body top targets the
//   buffer last read by tile t-2, already barrier-certified -> race-free.
// - T2 swizzle: chunk ^= (row>>1)&3 (both sides: pre-swizzled global source,
//   swizzled ds_read) -> 16-lane column reads spread over 8 bank-slots.
// - T5 setprio around MFMA cluster; T1 XCD swizzle, n0-inner.
// ---------------------------------------------------------------------------
#define ABUF 8192   // u16 elems per A buffer (256x32)
#define BBUF 4096   // u16 elems per B buffer (128x32)

template<bool GATHER_A>
__global__ __launch_bounds__(256, 2)
void gemm256_kernel(const u16* __restrict__ Abase, const u16* __restrict__ Wbase,
                    size_t wclass_stride, const float* __restrict__ bias_base,
                    int bias_stride, const int* __restrict__ offsets,
                    const int* __restrict__ rowidx, u16* __restrict__ Hout)
{
    __shared__ u16 sA[3 * ABUF];   // 48 KB
    __shared__ u16 sB[3 * BBUF];   // 24 KB
    const int tid = threadIdx.x;

    // XCD-chunked bijective swizzle (grid % 8 == 0), n0-inner
    const int bid = blockIdx.x;
    const int wg = (bid & 7) * ((int)gridDim.x >> 3) + (bid >> 3);
    const int m0 = (wg >> 3) * 256;
    const int n0 = (wg & 7) * 128;
    if (m0 >= offsets[CC]) return;
    int c = 0;
    while (m0 >= offsets[c + 1]) ++c;          // offsets are 256-multiples

    const int wv = tid >> 6, ln = tid & 63;
    const bool isA = (wv == 1 || wv == 2);
    const int nGld = isA ? 8 : 4;
    const int chunkBase = isA ? ((wv - 1) * 512) : ((wv == 3) ? 256 : 0);
    const int bufStep = isA ? ABUF : BBUF;
    u16* const ldsBase = isA ? sA : sB;
    const u16* const Wcl = Wbase + (size_t)c * wclass_stride;

    // staging precompute: per-thread global src (sans k-tile offset) + LDS dst
    const u16* gsrc[8];
    u16* ldst[8];
    #pragma unroll
    for (int j = 0; j < 8; ++j) {
        if (j < nGld) {
            const int n = chunkBase + j * 64 + ln;     // 16B-chunk index in tile
            const int row = n >> 2;
            const int logc = (n & 3) ^ ((row >> 1) & 3);  // inverse swizzle on src
            ldst[j] = ldsBase + n * 8;                 // linear LDS dest
            if (isA) {
                int grow = m0 + row;
                if (GATHER_A) { const int g = rowidx[grow]; grow = (g < 0) ? 0 : g; }
                gsrc[j] = Abase + (size_t)grow * 1024 + logc * 8;
            } else {
                gsrc[j] = Wcl + (size_t)(n0 + row) * 1024 + logc * 8;
            }
        } else { gsrc[j] = nullptr; ldst[j] = nullptr; }
    }

    // fragment read bases (swizzled): phys chunk = (ln>>4) ^ ((row>>1)&3),
    // constant across mi/ni since frag rows step by 16.
    const int wm = wv >> 1, wn = wv & 1, lr = ln & 15, lg = ln >> 4;
    const int arow0 = wm * 128 + lr;
    const int brow0 = wn * 64 + lr;
    const int pcA = lg ^ ((arow0 >> 1) & 3);
    const int pcB = lg ^ ((brow0 >> 1) & 3);
    const u16* const fA = sA + arow0 * 32 + pcA * 8;   // + mi*512 + p*ABUF
    const u16* const fB = sB + brow0 * 32 + pcB * 8;   // + ni*512 + p*BBUF

    f32x4 acc[8][4];
    #pragma unroll
    for (int i = 0; i < 8; ++i)
        #pragma unroll
        for (int j = 0; j < 4; ++j)
            acc[i][j] = (f32x4){0.f, 0.f, 0.f, 0.f};

#define STAGE6(KT, P)                                                     \
    {                                                                     \
        _Pragma("unroll")                                                 \
        for (int j = 0; j < 8; ++j)                                       \
            if (j < nGld) GLDS16(gsrc[j] + (KT) * 32, ldst[j] + (P) * bufStep); \
    }

#define COMPUTE6(P)                                                       \
    {                                                                     \
        bf16x8 bfr[4];                                                    \
        _Pragma("unroll")                                                 \
        for (int ni = 0; ni < 4; ++ni)                                    \
            bfr[ni] = *(const bf16x8*)(fB + (P) * BBUF + ni * 512);       \
        __builtin_amdgcn_s_setprio(1);                                    \
        _Pragma("unroll")                                                 \
        for (int mi = 0; mi < 8; ++mi) {                                  \
            const bf16x8 a = *(const bf16x8*)(fA + (P) * ABUF + mi * 512);\
            _Pragma("unroll")                                             \
            for (int ni = 0; ni < 4; ++ni)                                \
                acc[mi][ni] = __builtin_amdgcn_mfma_f32_16x16x32_bf16(    \
                    a, bfr[ni], acc[mi][ni], 0, 0, 0);                    \
        }                                                                 \
        __builtin_amdgcn_s_setprio(0);                                    \
    }

    // body: stage t+1 (buffer (t+1)%3, last read at t-2, certified by the
    // barrier in body t-1) -> own-count vmcnt -> barrier -> compute t.
#define BODY6(T, P, PN)                                                   \
    {                                                                     \
        STAGE6((T) + 1, (PN));                                            \
        if (isA) asm volatile("s_waitcnt vmcnt(8)" ::: "memory");         \
        else     asm volatile("s_waitcnt vmcnt(4)" ::: "memory");         \
        __builtin_amdgcn_s_barrier();                                     \
        __builtin_amdgcn_sched_barrier(0);                                \
        COMPUTE6(P);                                                      \
    }

    STAGE6(0, 0);                      // prologue: tile 0 -> buf 0
    for (int tb = 0; tb < 30; tb += 3) {
        BODY6(tb + 0, 0, 1);
        BODY6(tb + 1, 1, 2);
        BODY6(tb + 2, 2, 0);
    }
    BODY6(30, 0, 1);                   // stages tile 31 -> buf 1
    // tile 31: nothing left to stage; drain (once) is fine at the end
    asm volatile("s_waitcnt vmcnt(0)" ::: "memory");
    __builtin_amdgcn_s_barrier();
    __builtin_amdgcn_sched_barrier(0);
    COMPUTE6(1);

#undef BODY6
#undef COMPUTE6
#undef STAGE6

    // epilogue: C/D layout col=lane&15, row=(lane>>4)*4+reg; bias + ReLU
    const float* bp = bias_base + (size_t)c * bias_stride + n0 + wn * 64 + lr;
    #pragma unroll
    for (int ni = 0; ni < 4; ++ni) {
        const float bv = bp[ni * 16];
        const int col = n0 + wn * 64 + ni * 16 + lr;
        #pragma unroll
        for (int mi = 0; mi < 8; ++mi) {
            const int rb = m0 + wm * 128 + mi * 16 + lg * 4;
            #pragma unroll
            for (int q = 0; q < 4; ++q) {
                float v = acc[mi][ni][q] + bv;
                v = v > 0.f ? v : 0.f;
                Hout[(size_t)(rb + q) * HH + col] = f2bf(v);
            }
        }
    }
}

// ---------------------------------------------------------------------------
// L4 GEMM (N=256, final scatter): proven R5 structure, BM=BN=128, BK=32.
// ---------------------------------------------------------------------------
#define STAGE(b, kt)                            \
    {                                           \
        const int kb_ = (kt) * 32;              \
        GLDS16(gA0 + kb_, lA0 + (b) * 4096);    \
        GLDS16(gA1 + kb_, lA1 + (b) * 4096);    \
        GLDS16(gB0 + kb_, lB0 + (b) * 4096);    \
        GLDS16(gB1 + kb_, lB1 + (b) * 4096);    \
    }

#define COMPUTE(b)                                                        \
    {                                                                     \
        bf16x8 af[4], bfr[4];                                             \
        _Pragma("unroll")                                                 \
        for (int i = 0; i < 4; ++i) {                                     \
            af[i]  = *(const bf16x8*)(fA + (b) * 4096 + i * 16 * 32);     \
            bfr[i] = *(const bf16x8*)(fB + (b) * 4096 + i * 16 * 32);     \
        }                                                                 \
        __builtin_amdgcn_s_setprio(1);                                    \
        _Pragma("unroll")                                                 \
        for (int mi = 0; mi < 4; ++mi)                                    \
            _Pragma("unroll")                                             \
            for (int ni = 0; ni < 4; ++ni)                                \
                acc[mi][ni] = __builtin_amdgcn_mfma_f32_16x16x32_bf16(    \
                    af[mi], bfr[ni], acc[mi][ni], 0, 0, 0);               \
        __builtin_amdgcn_s_setprio(0);                                    \
    }

#define WAITV(N)                                                          \
    asm volatile("s_waitcnt vmcnt(" #N ")" ::: "memory");                 \
    __builtin_amdgcn_s_barrier();                                         \
    __builtin_amdgcn_sched_barrier(0);

__global__ __launch_bounds__(256, 3)
void gemm_final_kernel(const u16* __restrict__ Abase, const u16* __restrict__ Wbase,
                       size_t wclass_stride, const float* __restrict__ bias_base,
                       int bias_stride, const int* __restrict__ offsets,
                       const int* __restrict__ rowidx, float* __restrict__ Fout)
{
    __shared__ u16 sA[3 * 128 * 32];
    __shared__ u16 sB[3 * 128 * 32];
    const int tid = threadIdx.x;

    const int bid = blockIdx.x;
    const int wg = (bid & 7) * ((int)gridDim.x >> 3) + (bid >> 3);
    const int m0 = (wg >> 1) * 128;
    const int n0 = (wg & 1) * 128;
    if (m0 >= offsets[CC]) return;
    int c = 0;
    while (m0 >= offsets[c + 1]) ++c;

    const int srow = tid >> 2;
    const int kc8 = (tid & 3) * 8;
    const int sa0 = m0 + srow, sa1 = m0 + srow + 64;
    const u16* gA0 = Abase + (size_t)sa0 * 1024 + kc8;
    const u16* gA1 = Abase + (size_t)sa1 * 1024 + kc8;
    const u16* Wcl = Wbase + (size_t)c * wclass_stride;
    const u16* gB0 = Wcl + (size_t)(n0 + srow) * 1024 + kc8;
    const u16* gB1 = Wcl + (size_t)(n0 + srow + 64) * 1024 + kc8;
    u16* lA0 = sA + tid * 8;
    u16* lA1 = sA + 2048 + tid * 8;
    u16* lB0 = sB + tid * 8;
    u16* lB1 = sB + 2048 + tid * 8;

    const int lane = tid & 63, wv = tid >> 6;
    const int wm = (wv & 1) * 64, wn = (wv >> 1) * 64;
    const int lr = lane & 15, lg = lane >> 4;
    const u16* fA = sA + (wm + lr) * 32 + lg * 8;
    const u16* fB = sB + (wn + lr) * 32 + lg * 8;

    f32x4 acc[4][4];
    #pragma unroll
    for (int i = 0; i < 4; ++i)
        #pragma unroll
        for (int j = 0; j < 4; ++j)
            acc[i][j] = (f32x4){0.f, 0.f, 0.f, 0.f};

    STAGE(0, 0);
    STAGE(1, 1);
    for (int kt = 0; kt < 30; kt += 3) {
        WAITV(4);
        STAGE(2, kt + 2);
        COMPUTE(0);
        WAITV(4);
        STAGE(0, kt + 3);
        COMPUTE(1);
        WAITV(4);
        STAGE(1, kt + 4);
        COMPUTE(2);
    }
    WAITV(4);
    COMPUTE(0);
    WAITV(0);
    COMPUTE(1);

    const float* bp = bias_base + (size_t)c * bias_stride + n0 + wn + lr;
    #pragma unroll
    for (int ni = 0; ni < 4; ++ni) {
        const float bv = bp[ni * 16];
        const int col = n0 + wn + ni * 16 + lr;
        #pragma unroll
        for (int mi = 0; mi < 4; ++mi) {
            const int rb = m0 + wm + mi * 16 + lg * 4;
            #pragma unroll
            for (int q = 0; q < 4; ++q) {
                const float v = acc[mi][ni][q] + bv;
                const int orow = rowidx[rb + q];
                if (orow >= 0) Fout[(size_t)orow * OO + col] = v;
            }
        }
    }
}

// ---------------------------------------------------------------------------
extern "C" void kernel_launch(void* const* d_in, const int* in_sizes, int n_in,
                              void* d_out, int out_size, void* d_ws, size_t ws_size,
                              hipStream_t stream)
{
    const float* x  = (const float*)d_in[0];
    const float* Wc = (const float*)d_in[1];
    const float* bc = (const float*)d_in[2];
    const float* W1 = (const float*)d_in[3];
    const float* b1 = (const float*)d_in[4];
    const float* W2 = (const float*)d_in[5];
    const float* b2 = (const float*)d_in[6];
    const float* Wo = (const float*)d_in[7];
    const float* bo = (const float*)d_in[8];
    float* out    = (float*)d_out;                 // [B][O]
    float* logits = out + (size_t)BB * OO;         // [B][C]

    char* ws = (char*)d_ws;
    constexpr size_t PADMAX = BB + CC * 256;       // 18432 padded rows max
    constexpr int NLB = BB / 16;                   // 1024 logits blocks
    int* offsets   = (int*)(ws + 0);               // [9]
    int* hist      = (int*)(ws + 64);              // [NLB][8]
    int* bb        = (int*)(ws + 64 + NLB * 32);   // [NLB][8]
    int* class_idx = (int*)(ws + 64 + 2 * NLB * 32);
    int* rowidx    = (int*)((char*)class_idx + (size_t)BB * 4);
    u16* x_bf16    = (u16*)((char*)rowidx + PADMAX * 4);
    u16* hA  = x_bf16 + (size_t)BB * DD;
    u16* hB  = hA + PADMAX * HH;
    u16* W1T = hB + PADMAX * HH;                    // [C][H][D]
    u16* W2T = W1T + (size_t)CC * DD * HH;          // [C][2][H][H]
    u16* WoT = W2T + (size_t)CC * 2 * HH * HH;      // [C][O][H]

    hipMemsetAsync(rowidx, 0xFF, PADMAX * 4, stream);  // pad slots = -1

    transpose_bf16_kernel<<<dim3(32, 32, 8),  256, 0, stream>>>(W1, W1T, DD, HH);
    transpose_bf16_kernel<<<dim3(32, 32, 16), 256, 0, stream>>>(W2, W2T, HH, HH);
    transpose_bf16_kernel<<<dim3(8, 32, 8),   256, 0, stream>>>(Wo, WoT, HH, OO);

    logits_kernel<<<NLB, 256, 0, stream>>>(x, Wc, bc, logits, x_bf16, class_idx, hist);
    scan_kernel<<<1, 256, 0, stream>>>(hist, offsets, bb);
    scatter_kernel<<<BB / 256, 256, 0, stream>>>(class_idx, bb, rowidx);

    constexpr int MT2 = (int)(PADMAX / 256);  // 72 M-tiles (256-row)
    constexpr int MT4 = (int)(PADMAX / 128);  // 144 M-tiles (128-row, L4)
    gemm256_kernel<true ><<<dim3(MT2 * 8), 256, 0, stream>>>(
        x_bf16, W1T, (size_t)DD * HH, b1, HH, offsets, rowidx, hA);
    gemm256_kernel<false><<<dim3(MT2 * 8), 256, 0, stream>>>(
        hA, W2T, (size_t)2 * HH * HH, b2, 2 * HH, offsets, rowidx, hB);
    gemm256_kernel<false><<<dim3(MT2 * 8), 256, 0, stream>>>(
        hB, W2T + (size_t)HH * HH, (size_t)2 * HH * HH, b2 + HH, 2 * HH, offsets, rowidx, hA);
    gemm_final_kernel<<<dim3(MT4 * 2), 256, 0, stream>>>(
        hA, WoT, (size_t)OO * HH, bo, OO, offsets, rowidx, out);
}

// Round 7
// 356.985 us; speedup vs baseline: 1.0336x; 1.0336x over previous
//
#include <hip/hip_runtime.h>
#include <stdint.h>

// Problem constants
#define BB 16384
#define DD 1024
#define HH 1024
#define OO 256
#define CC 8

typedef unsigned short u16;
typedef __attribute__((ext_vector_type(4))) unsigned short u16x4;
typedef __attribute__((ext_vector_type(8))) short bf16x8;
typedef __attribute__((ext_vector_type(4))) float f32x4;

__device__ __forceinline__ u16 f2bf(float f) {
    union { float f; uint32_t u; } v; v.f = f;
    const uint32_t u = v.u;
    return (u16)((u + 0x7FFFu + ((u >> 16) & 1u)) >> 16);  // RNE
}

// async global->LDS, 16B per lane (dest must be wave-uniform base + lane*16)
#define GLDS16(g, l)                                                                   \
    __builtin_amdgcn_global_load_lds((const __attribute__((address_space(1))) void*)(g), \
                                     (__attribute__((address_space(3))) void*)(l), 16, 0, 0)

// ---------------------------------------------------------------------------
// Transpose fp32 [nmat][R][Cc] -> bf16 [nmat][Cc][R]  (W -> W^T, K-contiguous)
// ---------------------------------------------------------------------------
__global__ __launch_bounds__(256)
void transpose_bf16_kernel(const float* __restrict__ src, u16* __restrict__ dst,
                           int R, int Cc)
{
    __shared__ float t[32][33];
    const int tid = threadIdx.x;
    const int mat = blockIdx.z;
    const int r0 = blockIdx.y * 32, c0 = blockIdx.x * 32;
    {
        const int rr = tid >> 3, c4 = (tid & 7) * 4;
        const float4 v = *(const float4*)(src + ((size_t)mat * R + r0 + rr) * Cc + c0 + c4);
        t[rr][c4 + 0] = v.x; t[rr][c4 + 1] = v.y; t[rr][c4 + 2] = v.z; t[rr][c4 + 3] = v.w;
    }
    __syncthreads();
    {
        const int cc = tid >> 3, k4 = (tid & 7) * 4;
        u16x4 o;
        o[0] = f2bf(t[k4 + 0][cc]);
        o[1] = f2bf(t[k4 + 1][cc]);
        o[2] = f2bf(t[k4 + 2][cc]);
        o[3] = f2bf(t[k4 + 3][cc]);
        *(u16x4*)(dst + ((size_t)mat * Cc + c0 + cc) * R + r0 + k4) = o;
    }
}

// ---------------------------------------------------------------------------
// Logits (fp32, exact routing) + x -> bf16 + per-block class histogram.
// ---------------------------------------------------------------------------
__global__ __launch_bounds__(256)
void logits_kernel(const float* __restrict__ x, const float* __restrict__ Wc,
                   const float* __restrict__ bc, float* __restrict__ logits_out,
                   u16* __restrict__ x_bf16, int* __restrict__ class_idx,
                   int* __restrict__ hist)
{
    __shared__ float WcT[CC][DD];  // 32 KB, transposed classifier
    __shared__ int clsarr[16];
    const int tid = threadIdx.x;
    #pragma unroll
    for (int j = 0; j < 8; ++j) {
        const int f = tid + 256 * j;                 // float4 index into Wc [D][C]
        const float4 v = ((const float4*)Wc)[f];
        const int d = f >> 1, c = (f & 1) * 4;       // 4 elems share d (C=8)
        WcT[c + 0][d] = v.x; WcT[c + 1][d] = v.y; WcT[c + 2][d] = v.z; WcT[c + 3][d] = v.w;
    }
    __syncthreads();

    const int lane = tid & 63, wv = tid >> 6;
    const int row0 = blockIdx.x * 16 + wv * 4;

    float acc[4][8];
    #pragma unroll
    for (int r = 0; r < 4; ++r)
        #pragma unroll
        for (int c = 0; c < 8; ++c) acc[r][c] = 0.f;

    #pragma unroll
    for (int p = 0; p < 2; ++p) {
        float4 xv[2][4];
        #pragma unroll
        for (int rr = 0; rr < 2; ++rr) {
            const float4* xr = (const float4*)(x + (size_t)(row0 + 2 * p + rr) * DD);
            #pragma unroll
            for (int j = 0; j < 4; ++j) xv[rr][j] = xr[lane + 64 * j];
        }
        #pragma unroll
        for (int rr = 0; rr < 2; ++rr) {
            u16* xb = x_bf16 + (size_t)(row0 + 2 * p + rr) * DD;
            #pragma unroll
            for (int j = 0; j < 4; ++j) {
                const float4 v = xv[rr][j];
                u16x4 o; o[0] = f2bf(v.x); o[1] = f2bf(v.y); o[2] = f2bf(v.z); o[3] = f2bf(v.w);
                *(u16x4*)(xb + 4 * (lane + 64 * j)) = o;
            }
        }
        #pragma unroll
        for (int j = 0; j < 4; ++j) {
            const int f = lane + 64 * j;
            #pragma unroll
            for (int c = 0; c < 8; ++c) {
                const float4 w = *(const float4*)&WcT[c][4 * f];
                #pragma unroll
                for (int rr = 0; rr < 2; ++rr)
                    acc[2 * p + rr][c] += xv[rr][j].x * w.x + xv[rr][j].y * w.y
                                        + xv[rr][j].z * w.z + xv[rr][j].w * w.w;
            }
        }
    }

    #pragma unroll
    for (int off = 8; off < 64; off <<= 1)
        #pragma unroll
        for (int r = 0; r < 4; ++r)
            #pragma unroll
            for (int c = 0; c < 8; ++c)
                acc[r][c] += __shfl_xor(acc[r][c], off, 64);

    const int cls = lane >> 3;
    const float bcv = bc[cls];
    float s[4];
    #pragma unroll
    for (int r = 0; r < 4; ++r) {
        float v = acc[r][0];
        #pragma unroll
        for (int c = 1; c < 8; ++c) v = (cls == c) ? acc[r][c] : v;
        s[r] = v;
    }
    #pragma unroll
    for (int off = 1; off < 8; off <<= 1)
        #pragma unroll
        for (int r = 0; r < 4; ++r) s[r] += __shfl_xor(s[r], off, 64);
    #pragma unroll
    for (int r = 0; r < 4; ++r) s[r] += bcv;

    #pragma unroll
    for (int r = 0; r < 4; ++r)
        if ((lane & 7) == 0) logits_out[(size_t)(row0 + r) * CC + cls] = s[r];

    int idx[4] = {cls, cls, cls, cls};
    #pragma unroll
    for (int off = 8; off < 64; off <<= 1) {
        #pragma unroll
        for (int r = 0; r < 4; ++r) {
            const float ov = __shfl_xor(s[r], off, 64);
            const int oi = __shfl_xor(idx[r], off, 64);
            const bool take = (ov > s[r]) || (ov == s[r] && oi < idx[r]);
            s[r] = take ? ov : s[r];
            idx[r] = take ? oi : idx[r];
        }
    }
    if (lane == 0) {
        #pragma unroll
        for (int r = 0; r < 4; ++r) {
            class_idx[row0 + r] = idx[r];
            clsarr[wv * 4 + r] = idx[r];
        }
    }
    __syncthreads();
    if (tid < 64) {
        const int myc = (tid < 16) ? clsarr[tid] : -1;
        int h = 0;
        #pragma unroll
        for (int cc = 0; cc < 8; ++cc) {
            const int p = __popcll(__ballot(myc == cc));
            h = (tid == cc) ? p : h;
        }
        if (tid < 8) hist[blockIdx.x * 8 + tid] = h;
    }
}

// ---------------------------------------------------------------------------
// Single-block scan: per-class totals -> padded offsets (256-granular) +
// per-block scatter bases.
// ---------------------------------------------------------------------------
__global__ __launch_bounds__(256)
void scan_kernel(const int* __restrict__ hist, int* __restrict__ offsets,
                 int* __restrict__ bb)
{
    const int t = threadIdx.x, c = t >> 5, g = t & 31;
    int sum = 0;
    #pragma unroll 4
    for (int i = 0; i < 32; ++i) sum += hist[(g * 32 + i) * 8 + c];
    int inc = sum;
    #pragma unroll
    for (int d = 1; d < 32; d <<= 1) {
        const int v = __shfl_up(inc, d, 32);
        if (g >= d) inc += v;
    }
    __shared__ int tot[8], offL[9];
    if (g == 31) tot[c] = inc;
    __syncthreads();
    if (t == 0) {
        int o = 0; offL[0] = 0; offsets[0] = 0;
        #pragma unroll
        for (int c8 = 0; c8 < 8; ++c8) {
            o += (tot[c8] + 255) & ~255;          // pad to 256 (BM of layer GEMMs)
            offL[c8 + 1] = o; offsets[c8 + 1] = o;
        }
    }
    __syncthreads();
    int base = offL[c] + (inc - sum);
    #pragma unroll 4
    for (int i = 0; i < 32; ++i) {
        const int b = g * 32 + i;
        bb[b * 8 + c] = base;
        base += hist[b * 8 + c];
    }
}

// ---------------------------------------------------------------------------
// Scatter row ids into per-class segments — atomic-free via ballot ranking.
// ---------------------------------------------------------------------------
__global__ __launch_bounds__(256)
void scatter_kernel(const int* __restrict__ class_idx, const int* __restrict__ bb,
                    int* __restrict__ rowidx)
{
    const int r = blockIdx.x * 256 + threadIdx.x;
    const int c = class_idx[r];
    const int lane = threadIdx.x & 63;
    const int gl = lane & ~15;
    const unsigned long long before = (1ull << lane) - (1ull << gl);
    int rank = 0;
    #pragma unroll
    for (int cc = 0; cc < 8; ++cc) {
        const unsigned long long m = __ballot(c == cc);
        const int p = __popcll(m & before);
        rank = (c == cc) ? p : rank;
    }
    rowidx[bb[(r >> 4) * 8 + c] + rank] = r;
}

// ---------------------------------------------------------------------------
// R7 main GEMM (layers 1-3): BM=256, BN=128, BK=32, 4 waves, wave=128x64.
// Fix vs R6: restore DEPTH-2 prefetch with stage-AFTER-barrier (R5's proven
// schedule). Body for tile t: own-count vmcnt (A:8, B:4 = one tile in
// flight, never 0 until tail) -> s_barrier (certifies tile t landed AND
// buf (t-1)%3 fully read) -> STAGE tile t+2 into buf (t+2)%3 == (t-1)%3
// -> COMPUTE tile t. Tile t+2 thus has ~2 bodies (>800 cy) of cover.
// Kept from R6 (validated): T2 swizzle (conflicts 4.3M -> 0), role-split
// staging, T5 setprio, T1 XCD swizzle.
// ---------------------------------------------------------------------------
#define ABUF 8192   // u16 elems per A buffer (256x32)
#define BBUF 4096   // u16 elems per B buffer (128x32)

template<bool GATHER_A>
__global__ __launch_bounds__(256, 2)
void gemm256_kernel(const u16* __restrict__ Abase, const u16* __restrict__ Wbase,
                    size_t wclass_stride, const float* __restrict__ bias_base,
                    int bias_stride, const int* __restrict__ offsets,
                    const int* __restrict__ rowidx, u16* __restrict__ Hout)
{
    __shared__ u16 sA[3 * ABUF];   // 48 KB
    __shared__ u16 sB[3 * BBUF];   // 24 KB
    const int tid = threadIdx.x;

    // XCD-chunked bijective swizzle (grid % 8 == 0), n0-inner
    const int bid = blockIdx.x;
    const int wg = (bid & 7) * ((int)gridDim.x >> 3) + (bid >> 3);
    const int m0 = (wg >> 3) * 256;
    const int n0 = (wg & 7) * 128;
    if (m0 >= offsets[CC]) return;
    int c = 0;
    while (m0 >= offsets[c + 1]) ++c;          // offsets are 256-multiples

    const int wv = tid >> 6, ln = tid & 63;
    const bool isA = (wv == 1 || wv == 2);
    const int nGld = isA ? 8 : 4;
    const int chunkBase = isA ? ((wv - 1) * 512) : ((wv == 3) ? 256 : 0);
    const int bufStep = isA ? ABUF : BBUF;
    u16* const ldsBase = isA ? sA : sB;
    const u16* const Wcl = Wbase + (size_t)c * wclass_stride;

    // staging precompute: per-thread global src (sans k-tile offset) + LDS dst
    const u16* gsrc[8];
    u16* ldst[8];
    #pragma unroll
    for (int j = 0; j < 8; ++j) {
        if (j < nGld) {
            const int n = chunkBase + j * 64 + ln;     // 16B-chunk index in tile
            const int row = n >> 2;
            const int logc = (n & 3) ^ ((row >> 1) & 3);  // inverse swizzle on src
            ldst[j] = ldsBase + n * 8;                 // linear LDS dest
            if (isA) {
                int grow = m0 + row;
                if (GATHER_A) { const int g = rowidx[grow]; grow = (g < 0) ? 0 : g; }
                gsrc[j] = Abase + (size_t)grow * 1024 + logc * 8;
            } else {
                gsrc[j] = Wcl + (size_t)(n0 + row) * 1024 + logc * 8;
            }
        } else { gsrc[j] = nullptr; ldst[j] = nullptr; }
    }

    // fragment read bases (swizzled): phys chunk = (ln>>4) ^ ((row>>1)&3),
    // constant across mi/ni since frag rows step by 16.
    const int wm = wv >> 1, wn = wv & 1, lr = ln & 15, lg = ln >> 4;
    const int arow0 = wm * 128 + lr;
    const int brow0 = wn * 64 + lr;
    const int pcA = lg ^ ((arow0 >> 1) & 3);
    const int pcB = lg ^ ((brow0 >> 1) & 3);
    const u16* const fA = sA + arow0 * 32 + pcA * 8;   // + mi*512 + p*ABUF
    const u16* const fB = sB + brow0 * 32 + pcB * 8;   // + ni*512 + p*BBUF

    f32x4 acc[8][4];
    #pragma unroll
    for (int i = 0; i < 8; ++i)
        #pragma unroll
        for (int j = 0; j < 4; ++j)
            acc[i][j] = (f32x4){0.f, 0.f, 0.f, 0.f};

#define STAGE6(KT, P)                                                     \
    {                                                                     \
        _Pragma("unroll")                                                 \
        for (int j = 0; j < 8; ++j)                                       \
            if (j < nGld) GLDS16(gsrc[j] + (KT) * 32, ldst[j] + (P) * bufStep); \
    }

#define COMPUTE6(P)                                                       \
    {                                                                     \
        bf16x8 bfr[4];                                                    \
        _Pragma("unroll")                                                 \
        for (int ni = 0; ni < 4; ++ni)                                    \
            bfr[ni] = *(const bf16x8*)(fB + (P) * BBUF + ni * 512);       \
        __builtin_amdgcn_s_setprio(1);                                    \
        _Pragma("unroll")                                                 \
        for (int mi = 0; mi < 8; ++mi) {                                  \
            const bf16x8 a = *(const bf16x8*)(fA + (P) * ABUF + mi * 512);\
            _Pragma("unroll")                                             \
            for (int ni = 0; ni < 4; ++ni)                                \
                acc[mi][ni] = __builtin_amdgcn_mfma_f32_16x16x32_bf16(    \
                    a, bfr[ni], acc[mi][ni], 0, 0, 0);                    \
        }                                                                 \
        __builtin_amdgcn_s_setprio(0);                                    \
    }

    // own-count wait (one tile's loads still allowed in flight) + barrier
#define WAITOWN                                                           \
    if (isA) asm volatile("s_waitcnt vmcnt(8)" ::: "memory");             \
    else     asm volatile("s_waitcnt vmcnt(4)" ::: "memory");             \
    __builtin_amdgcn_s_barrier();                                         \
    __builtin_amdgcn_sched_barrier(0);

    // prologue: depth-2 (tiles 0,1 in flight)
    STAGE6(0, 0);
    STAGE6(1, 1);
    for (int tb = 0; tb < 30; tb += 3) {
        WAITOWN; STAGE6(tb + 2, 2); COMPUTE6(0);   // compute t=tb
        WAITOWN; STAGE6(tb + 3, 0); COMPUTE6(1);   // compute t=tb+1
        WAITOWN; STAGE6(tb + 4, 1); COMPUTE6(2);   // compute t=tb+2
    }
    WAITOWN;                                        // tile 30 landed
    COMPUTE6(0);
    asm volatile("s_waitcnt vmcnt(0)" ::: "memory");  // tile 31 (tail only)
    __builtin_amdgcn_s_barrier();
    __builtin_amdgcn_sched_barrier(0);
    COMPUTE6(1);

#undef WAITOWN
#undef COMPUTE6
#undef STAGE6

    // epilogue: C/D layout col=lane&15, row=(lane>>4)*4+reg; bias + ReLU
    const float* bp = bias_base + (size_t)c * bias_stride + n0 + wn * 64 + lr;
    #pragma unroll
    for (int ni = 0; ni < 4; ++ni) {
        const float bv = bp[ni * 16];
        const int col = n0 + wn * 64 + ni * 16 + lr;
        #pragma unroll
        for (int mi = 0; mi < 8; ++mi) {
            const int rb = m0 + wm * 128 + mi * 16 + lg * 4;
            #pragma unroll
            for (int q = 0; q < 4; ++q) {
                float v = acc[mi][ni][q] + bv;
                v = v > 0.f ? v : 0.f;
                Hout[(size_t)(rb + q) * HH + col] = f2bf(v);
            }
        }
    }
}

// ---------------------------------------------------------------------------
// L4 GEMM (N=256, final scatter): proven R5 structure, BM=BN=128, BK=32.
// ---------------------------------------------------------------------------
#define STAGE(b, kt)                            \
    {                                           \
        const int kb_ = (kt) * 32;              \
        GLDS16(gA0 + kb_, lA0 + (b) * 4096);    \
        GLDS16(gA1 + kb_, lA1 + (b) * 4096);    \
        GLDS16(gB0 + kb_, lB0 + (b) * 4096);    \
        GLDS16(gB1 + kb_, lB1 + (b) * 4096);    \
    }

#define COMPUTE(b)                                                        \
    {                                                                     \
        bf16x8 af[4], bfr[4];                                             \
        _Pragma("unroll")                                                 \
        for (int i = 0; i < 4; ++i) {                                     \
            af[i]  = *(const bf16x8*)(fA + (b) * 4096 + i * 16 * 32);     \
            bfr[i] = *(const bf16x8*)(fB + (b) * 4096 + i * 16 * 32);     \
        }                                                                 \
        __builtin_amdgcn_s_setprio(1);                                    \
        _Pragma("unroll")                                                 \
        for (int mi = 0; mi < 4; ++mi)                                    \
            _Pragma("unroll")                                             \
            for (int ni = 0; ni < 4; ++ni)                                \
                acc[mi][ni] = __builtin_amdgcn_mfma_f32_16x16x32_bf16(    \
                    af[mi], bfr[ni], acc[mi][ni], 0, 0, 0);               \
        __builtin_amdgcn_s_setprio(0);                                    \
    }

#define WAITV(N)                                                          \
    asm volatile("s_waitcnt vmcnt(" #N ")" ::: "memory");                 \
    __builtin_amdgcn_s_barrier();                                         \
    __builtin_amdgcn_sched_barrier(0);

__global__ __launch_bounds__(256, 3)
void gemm_final_kernel(const u16* __restrict__ Abase, const u16* __restrict__ Wbase,
                       size_t wclass_stride, const float* __restrict__ bias_base,
                       int bias_stride, const int* __restrict__ offsets,
                       const int* __restrict__ rowidx, float* __restrict__ Fout)
{
    __shared__ u16 sA[3 * 128 * 32];
    __shared__ u16 sB[3 * 128 * 32];
    const int tid = threadIdx.x;

    const int bid = blockIdx.x;
    const int wg = (bid & 7) * ((int)gridDim.x >> 3) + (bid >> 3);
    const int m0 = (wg >> 1) * 128;
    const int n0 = (wg & 1) * 128;
    if (m0 >= offsets[CC]) return;
    int c = 0;
    while (m0 >= offsets[c + 1]) ++c;

    const int srow = tid >> 2;
    const int kc8 = (tid & 3) * 8;
    const int sa0 = m0 + srow, sa1 = m0 + srow + 64;
    const u16* gA0 = Abase + (size_t)sa0 * 1024 + kc8;
    const u16* gA1 = Abase + (size_t)sa1 * 1024 + kc8;
    const u16* Wcl = Wbase + (size_t)c * wclass_stride;
    const u16* gB0 = Wcl + (size_t)(n0 + srow) * 1024 + kc8;
    const u16* gB1 = Wcl + (size_t)(n0 + srow + 64) * 1024 + kc8;
    u16* lA0 = sA + tid * 8;
    u16* lA1 = sA + 2048 + tid * 8;
    u16* lB0 = sB + tid * 8;
    u16* lB1 = sB + 2048 + tid * 8;

    const int lane = tid & 63, wv = tid >> 6;
    const int wm = (wv & 1) * 64, wn = (wv >> 1) * 64;
    const int lr = lane & 15, lg = lane >> 4;
    const u16* fA = sA + (wm + lr) * 32 + lg * 8;
    const u16* fB = sB + (wn + lr) * 32 + lg * 8;

    f32x4 acc[4][4];
    #pragma unroll
    for (int i = 0; i < 4; ++i)
        #pragma unroll
        for (int j = 0; j < 4; ++j)
            acc[i][j] = (f32x4){0.f, 0.f, 0.f, 0.f};

    STAGE(0, 0);
    STAGE(1, 1);
    for (int kt = 0; kt < 30; kt += 3) {
        WAITV(4);
        STAGE(2, kt + 2);
        COMPUTE(0);
        WAITV(4);
        STAGE(0, kt + 3);
        COMPUTE(1);
        WAITV(4);
        STAGE(1, kt + 4);
        COMPUTE(2);
    }
    WAITV(4);
    COMPUTE(0);
    WAITV(0);
    COMPUTE(1);

    const float* bp = bias_base + (size_t)c * bias_stride + n0 + wn + lr;
    #pragma unroll
    for (int ni = 0; ni < 4; ++ni) {
        const float bv = bp[ni * 16];
        const int col = n0 + wn + ni * 16 + lr;
        #pragma unroll
        for (int mi = 0; mi < 4; ++mi) {
            const int rb = m0 + wm + mi * 16 + lg * 4;
            #pragma unroll
            for (int q = 0; q < 4; ++q) {
                const float v = acc[mi][ni][q] + bv;
                const int orow = rowidx[rb + q];
                if (orow >= 0) Fout[(size_t)orow * OO + col] = v;
            }
        }
    }
}

// ---------------------------------------------------------------------------
extern "C" void kernel_launch(void* const* d_in, const int* in_sizes, int n_in,
                              void* d_out, int out_size, void* d_ws, size_t ws_size,
                              hipStream_t stream)
{
    const float* x  = (const float*)d_in[0];
    const float* Wc = (const float*)d_in[1];
    const float* bc = (const float*)d_in[2];
    const float* W1 = (const float*)d_in[3];
    const float* b1 = (const float*)d_in[4];
    const float* W2 = (const float*)d_in[5];
    const float* b2 = (const float*)d_in[6];
    const float* Wo = (const float*)d_in[7];
    const float* bo = (const float*)d_in[8];
    float* out    = (float*)d_out;                 // [B][O]
    float* logits = out + (size_t)BB * OO;         // [B][C]

    char* ws = (char*)d_ws;
    constexpr size_t PADMAX = BB + CC * 256;       // 18432 padded rows max
    constexpr int NLB = BB / 16;                   // 1024 logits blocks
    int* offsets   = (int*)(ws + 0);               // [9]
    int* hist      = (int*)(ws + 64);              // [NLB][8]
    int* bb        = (int*)(ws + 64 + NLB * 32);   // [NLB][8]
    int* class_idx = (int*)(ws + 64 + 2 * NLB * 32);
    int* rowidx    = (int*)((char*)class_idx + (size_t)BB * 4);
    u16* x_bf16    = (u16*)((char*)rowidx + PADMAX * 4);
    u16* hA  = x_bf16 + (size_t)BB * DD;
    u16* hB  = hA + PADMAX * HH;
    u16* W1T = hB + PADMAX * HH;                    // [C][H][D]
    u16* W2T = W1T + (size_t)CC * DD * HH;          // [C][2][H][H]
    u16* WoT = W2T + (size_t)CC * 2 * HH * HH;      // [C][O][H]

    hipMemsetAsync(rowidx, 0xFF, PADMAX * 4, stream);  // pad slots = -1

    transpose_bf16_kernel<<<dim3(32, 32, 8),  256, 0, stream>>>(W1, W1T, DD, HH);
    transpose_bf16_kernel<<<dim3(32, 32, 16), 256, 0, stream>>>(W2, W2T, HH, HH);
    transpose_bf16_kernel<<<dim3(8, 32, 8),   256, 0, stream>>>(Wo, WoT, HH, OO);

    logits_kernel<<<NLB, 256, 0, stream>>>(x, Wc, bc, logits, x_bf16, class_idx, hist);
    scan_kernel<<<1, 256, 0, stream>>>(hist, offsets, bb);
    scatter_kernel<<<BB / 256, 256, 0, stream>>>(class_idx, bb, rowidx);

    constexpr int MT2 = (int)(PADMAX / 256);  // 72 M-tiles (256-row)
    constexpr int MT4 = (int)(PADMAX / 128);  // 144 M-tiles (128-row, L4)
    gemm256_kernel<true ><<<dim3(MT2 * 8), 256, 0, stream>>>(
        x_bf16, W1T, (size_t)DD * HH, b1, HH, offsets, rowidx, hA);
    gemm256_kernel<false><<<dim3(MT2 * 8), 256, 0, stream>>>(
        hA, W2T, (size_t)2 * HH * HH, b2, 2 * HH, offsets, rowidx, hB);
    gemm256_kernel<false><<<dim3(MT2 * 8), 256, 0, stream>>>(
        hB, W2T + (size_t)HH * HH, (size_t)2 * HH * HH, b2 + HH, 2 * HH, offsets, rowidx, hA);
    gemm_final_kernel<<<dim3(MT4 * 2), 256, 0, stream>>>(
        hA, WoT, (size_t)OO * HH, bo, OO, offsets, rowidx, out);
}

// Round 8
// 313.647 us; speedup vs baseline: 1.1764x; 1.1382x over previous
//
#include <hip/hip_runtime.h>
#include <stdint.h>

// Problem constants
#define BB 16384
#define DD 1024
#define HH 1024
#define OO 256
#define CC 8

typedef unsigned short u16;
typedef __attribute__((ext_vector_type(4))) unsigned short u16x4;
typedef __attribute__((ext_vector_type(8))) short bf16x8;
typedef __attribute__((ext_vector_type(4))) float f32x4;

__device__ __forceinline__ u16 f2bf(float f) {
    union { float f; uint32_t u; } v; v.f = f;
    const uint32_t u = v.u;
    return (u16)((u + 0x7FFFu + ((u >> 16) & 1u)) >> 16);  // RNE
}

// async global->LDS, 16B per lane (dest must be wave-uniform base + lane*16)
#define GLDS16(g, l)                                                                   \
    __builtin_amdgcn_global_load_lds((const __attribute__((address_space(1))) void*)(g), \
                                     (__attribute__((address_space(3))) void*)(l), 16, 0, 0)

// ---------------------------------------------------------------------------
// Transpose fp32 [nmat][R][Cc] -> bf16 [nmat][Cc][R]  (W -> W^T, K-contiguous)
// ---------------------------------------------------------------------------
__global__ __launch_bounds__(256)
void transpose_bf16_kernel(const float* __restrict__ src, u16* __restrict__ dst,
                           int R, int Cc)
{
    __shared__ float t[32][33];
    const int tid = threadIdx.x;
    const int mat = blockIdx.z;
    const int r0 = blockIdx.y * 32, c0 = blockIdx.x * 32;
    {
        const int rr = tid >> 3, c4 = (tid & 7) * 4;
        const float4 v = *(const float4*)(src + ((size_t)mat * R + r0 + rr) * Cc + c0 + c4);
        t[rr][c4 + 0] = v.x; t[rr][c4 + 1] = v.y; t[rr][c4 + 2] = v.z; t[rr][c4 + 3] = v.w;
    }
    __syncthreads();
    {
        const int cc = tid >> 3, k4 = (tid & 7) * 4;
        u16x4 o;
        o[0] = f2bf(t[k4 + 0][cc]);
        o[1] = f2bf(t[k4 + 1][cc]);
        o[2] = f2bf(t[k4 + 2][cc]);
        o[3] = f2bf(t[k4 + 3][cc]);
        *(u16x4*)(dst + ((size_t)mat * Cc + c0 + cc) * R + r0 + k4) = o;
    }
}

// ---------------------------------------------------------------------------
// Logits (fp32, exact routing) + x -> bf16 + per-block class histogram.
// ---------------------------------------------------------------------------
__global__ __launch_bounds__(256)
void logits_kernel(const float* __restrict__ x, const float* __restrict__ Wc,
                   const float* __restrict__ bc, float* __restrict__ logits_out,
                   u16* __restrict__ x_bf16, int* __restrict__ class_idx,
                   int* __restrict__ hist)
{
    __shared__ float WcT[CC][DD];  // 32 KB, transposed classifier
    __shared__ int clsarr[16];
    const int tid = threadIdx.x;
    #pragma unroll
    for (int j = 0; j < 8; ++j) {
        const int f = tid + 256 * j;                 // float4 index into Wc [D][C]
        const float4 v = ((const float4*)Wc)[f];
        const int d = f >> 1, c = (f & 1) * 4;       // 4 elems share d (C=8)
        WcT[c + 0][d] = v.x; WcT[c + 1][d] = v.y; WcT[c + 2][d] = v.z; WcT[c + 3][d] = v.w;
    }
    __syncthreads();

    const int lane = tid & 63, wv = tid >> 6;
    const int row0 = blockIdx.x * 16 + wv * 4;

    float acc[4][8];
    #pragma unroll
    for (int r = 0; r < 4; ++r)
        #pragma unroll
        for (int c = 0; c < 8; ++c) acc[r][c] = 0.f;

    #pragma unroll
    for (int p = 0; p < 2; ++p) {
        float4 xv[2][4];
        #pragma unroll
        for (int rr = 0; rr < 2; ++rr) {
            const float4* xr = (const float4*)(x + (size_t)(row0 + 2 * p + rr) * DD);
            #pragma unroll
            for (int j = 0; j < 4; ++j) xv[rr][j] = xr[lane + 64 * j];
        }
        #pragma unroll
        for (int rr = 0; rr < 2; ++rr) {
            u16* xb = x_bf16 + (size_t)(row0 + 2 * p + rr) * DD;
            #pragma unroll
            for (int j = 0; j < 4; ++j) {
                const float4 v = xv[rr][j];
                u16x4 o; o[0] = f2bf(v.x); o[1] = f2bf(v.y); o[2] = f2bf(v.z); o[3] = f2bf(v.w);
                *(u16x4*)(xb + 4 * (lane + 64 * j)) = o;
            }
        }
        #pragma unroll
        for (int j = 0; j < 4; ++j) {
            const int f = lane + 64 * j;
            #pragma unroll
            for (int c = 0; c < 8; ++c) {
                const float4 w = *(const float4*)&WcT[c][4 * f];
                #pragma unroll
                for (int rr = 0; rr < 2; ++rr)
                    acc[2 * p + rr][c] += xv[rr][j].x * w.x + xv[rr][j].y * w.y
                                        + xv[rr][j].z * w.z + xv[rr][j].w * w.w;
            }
        }
    }

    #pragma unroll
    for (int off = 8; off < 64; off <<= 1)
        #pragma unroll
        for (int r = 0; r < 4; ++r)
            #pragma unroll
            for (int c = 0; c < 8; ++c)
                acc[r][c] += __shfl_xor(acc[r][c], off, 64);

    const int cls = lane >> 3;
    const float bcv = bc[cls];
    float s[4];
    #pragma unroll
    for (int r = 0; r < 4; ++r) {
        float v = acc[r][0];
        #pragma unroll
        for (int c = 1; c < 8; ++c) v = (cls == c) ? acc[r][c] : v;
        s[r] = v;
    }
    #pragma unroll
    for (int off = 1; off < 8; off <<= 1)
        #pragma unroll
        for (int r = 0; r < 4; ++r) s[r] += __shfl_xor(s[r], off, 64);
    #pragma unroll
    for (int r = 0; r < 4; ++r) s[r] += bcv;

    #pragma unroll
    for (int r = 0; r < 4; ++r)
        if ((lane & 7) == 0) logits_out[(size_t)(row0 + r) * CC + cls] = s[r];

    int idx[4] = {cls, cls, cls, cls};
    #pragma unroll
    for (int off = 8; off < 64; off <<= 1) {
        #pragma unroll
        for (int r = 0; r < 4; ++r) {
            const float ov = __shfl_xor(s[r], off, 64);
            const int oi = __shfl_xor(idx[r], off, 64);
            const bool take = (ov > s[r]) || (ov == s[r] && oi < idx[r]);
            s[r] = take ? ov : s[r];
            idx[r] = take ? oi : idx[r];
        }
    }
    if (lane == 0) {
        #pragma unroll
        for (int r = 0; r < 4; ++r) {
            class_idx[row0 + r] = idx[r];
            clsarr[wv * 4 + r] = idx[r];
        }
    }
    __syncthreads();
    if (tid < 64) {
        const int myc = (tid < 16) ? clsarr[tid] : -1;
        int h = 0;
        #pragma unroll
        for (int cc = 0; cc < 8; ++cc) {
            const int p = __popcll(__ballot(myc == cc));
            h = (tid == cc) ? p : h;
        }
        if (tid < 8) hist[blockIdx.x * 8 + tid] = h;
    }
}

// ---------------------------------------------------------------------------
// Single-block scan: per-class totals -> padded offsets (256-granular) +
// per-block scatter bases.
// ---------------------------------------------------------------------------
__global__ __launch_bounds__(256)
void scan_kernel(const int* __restrict__ hist, int* __restrict__ offsets,
                 int* __restrict__ bb)
{
    const int t = threadIdx.x, c = t >> 5, g = t & 31;
    int sum = 0;
    #pragma unroll 4
    for (int i = 0; i < 32; ++i) sum += hist[(g * 32 + i) * 8 + c];
    int inc = sum;
    #pragma unroll
    for (int d = 1; d < 32; d <<= 1) {
        const int v = __shfl_up(inc, d, 32);
        if (g >= d) inc += v;
    }
    __shared__ int tot[8], offL[9];
    if (g == 31) tot[c] = inc;
    __syncthreads();
    if (t == 0) {
        int o = 0; offL[0] = 0; offsets[0] = 0;
        #pragma unroll
        for (int c8 = 0; c8 < 8; ++c8) {
            o += (tot[c8] + 255) & ~255;          // pad to 256 (BM of layer GEMMs)
            offL[c8 + 1] = o; offsets[c8 + 1] = o;
        }
    }
    __syncthreads();
    int base = offL[c] + (inc - sum);
    #pragma unroll 4
    for (int i = 0; i < 32; ++i) {
        const int b = g * 32 + i;
        bb[b * 8 + c] = base;
        base += hist[b * 8 + c];
    }
}

// ---------------------------------------------------------------------------
// Scatter row ids into per-class segments — atomic-free via ballot ranking.
// ---------------------------------------------------------------------------
__global__ __launch_bounds__(256)
void scatter_kernel(const int* __restrict__ class_idx, const int* __restrict__ bb,
                    int* __restrict__ rowidx)
{
    const int r = blockIdx.x * 256 + threadIdx.x;
    const int c = class_idx[r];
    const int lane = threadIdx.x & 63;
    const int gl = lane & ~15;
    const unsigned long long before = (1ull << lane) - (1ull << gl);
    int rank = 0;
    #pragma unroll
    for (int cc = 0; cc < 8; ++cc) {
        const unsigned long long m = __ballot(c == cc);
        const int p = __popcll(m & before);
        rank = (c == cc) ? p : rank;
    }
    rowidx[bb[(r >> 4) * 8 + c] + rank] = r;
}

// ---------------------------------------------------------------------------
// R8 main GEMM (layers 1-3): 8-phase-style schedule (m201/m248 lineage).
// BM=256, BN=128, BK=64, 512 threads / 8 waves (4M x 2N), wave out 64x64.
// 3 LDS buffers (A 3x32KB + B 3x16KB = 144KB, 1 block/CU).
// Per K-tile: 1 barrier + per-thread vmcnt(6) (6 glds/thread/tile; next
// tile's 6 ALWAYS in flight), then 4 unsynced phases of
// {stage-issue, ds_read(6/2/6/2 snake), setprio(1) 8xMFMA setprio(0)}.
// Stage target buf (t+2)%3 was last read at tile t-1, certified by the
// top-of-t barrier -> race-free with depth-2 cover (~2 K-tiles).
// Swizzle: phys_chunk = logical_chunk ^ (row&7) both sides (R6-validated,
// conflicts 4.3M -> 0). T1 XCD swizzle, n0-inner.
// ---------------------------------------------------------------------------
#define TA (256 * 64)   // u16 elems per A buffer (32 KB)
#define TB (128 * 64)   // u16 elems per B buffer (16 KB)
#define MF(a, b, c) __builtin_amdgcn_mfma_f32_16x16x32_bf16((a), (b), (c), 0, 0, 0)

template<bool GATHER_A>
__global__ __launch_bounds__(512, 2)
void gemm8p_kernel(const u16* __restrict__ Abase, const u16* __restrict__ Wbase,
                   size_t wclass_stride, const float* __restrict__ bias_base,
                   int bias_stride, const int* __restrict__ offsets,
                   const int* __restrict__ rowidx, u16* __restrict__ Hout)
{
    __shared__ u16 sA[3 * TA];   // 96 KB
    __shared__ u16 sB[3 * TB];   // 48 KB
    const int tid = threadIdx.x;

    // XCD-chunked bijective swizzle (grid % 8 == 0), n0-inner
    const int bid = blockIdx.x;
    const int wg = (bid & 7) * ((int)gridDim.x >> 3) + (bid >> 3);
    const int m0 = (wg >> 3) * 256;
    const int n0 = (wg & 7) * 128;
    if (m0 >= offsets[CC]) return;
    int c = 0;
    while (m0 >= offsets[c + 1]) ++c;          // offsets are 256-multiples

    // ---- staging precompute: 6 glds/thread/tile ----
    // j=0..3: A chunks tid+512j (2048 chunks = 256 rows x 8); j=4,5: B chunks.
    const u16* gsrc[6];
    u16* ldst[6];
    const u16* const Wcl = Wbase + (size_t)c * wclass_stride;
    #pragma unroll
    for (int j = 0; j < 6; ++j) {
        if (j < 4) {
            const int n = tid + 512 * j;
            const int row = n >> 3;
            const int logc = (n & 7) ^ (row & 7);   // inverse swizzle on source
            int grow = m0 + row;
            if (GATHER_A) { const int g = rowidx[grow]; grow = (g < 0) ? 0 : g; }
            gsrc[j] = Abase + (size_t)grow * 1024 + logc * 8;
            ldst[j] = sA + n * 8;                   // linear LDS dest
        } else {
            const int n = tid + 512 * (j - 4);
            const int row = n >> 3;
            const int logc = (n & 7) ^ (row & 7);
            gsrc[j] = Wcl + (size_t)(n0 + row) * 1024 + logc * 8;
            ldst[j] = sB + n * 8;
        }
    }

    // ---- fragment read offsets (swizzled) ----
    const int wv = tid >> 6, ln = tid & 63;
    const int wm = wv >> 1, wn = wv & 1;           // 4M x 2N wave grid
    const int lr = ln & 15, lg = ln >> 4;
    const int s = lr & 7;
    // phys chunk for (kh, lg) at row r: (kh*4 + lg) ^ (r&7); r&7 == lr&7
    const int aoff0 = (wm * 64 + lr) * 64 + ((0 ^ (lg ^ s)) * 8);
    const int aoff1 = (wm * 64 + lr) * 64 + ((4 ^ (lg ^ s)) * 8);
    const int boff0 = (wn * 64 + lr) * 64 + ((0 ^ (lg ^ s)) * 8);
    const int boff1 = (wn * 64 + lr) * 64 + ((4 ^ (lg ^ s)) * 8);

    f32x4 acc[4][4];
    #pragma unroll
    for (int i = 0; i < 4; ++i)
        #pragma unroll
        for (int j = 0; j < 4; ++j)
            acc[i][j] = (f32x4){0.f, 0.f, 0.f, 0.f};

#define STJ8(J, KT, SB) \
    GLDS16(gsrc[J] + (KT) * 64, ldst[J] + (SB) * ((J) < 4 ? TA : TB))

#define STAGEALL8(KT, SB) \
    { STJ8(0, KT, SB); STJ8(1, KT, SB); STJ8(2, KT, SB); STJ8(3, KT, SB); \
      STJ8(4, KT, SB); STJ8(5, KT, SB); }

    // One K-tile: wait own vmcnt -> barrier -> 4 phases.
#define TILE8(VM, BUF, KT2, SB, DOST)                                         \
    {                                                                         \
        asm volatile("s_waitcnt vmcnt(" #VM ")" ::: "memory");                \
        __builtin_amdgcn_s_barrier();                                         \
        __builtin_amdgcn_sched_barrier(0);                                    \
        const u16* const pA0 = sA + (BUF) * TA + aoff0;                       \
        const u16* const pA1 = sA + (BUF) * TA + aoff1;                       \
        const u16* const pB0 = sB + (BUF) * TB + boff0;                       \
        const u16* const pB1 = sB + (BUF) * TB + boff1;                       \
        bf16x8 av0, av1, av2, av3, bv0, bv1;                                  \
        /* phase 0: kh0 x ni{0,1} */                                          \
        if (DOST) { STJ8(0, KT2, SB); STJ8(1, KT2, SB); }                     \
        av0 = *(const bf16x8*)(pA0);                                          \
        av1 = *(const bf16x8*)(pA0 + 1024);                                   \
        av2 = *(const bf16x8*)(pA0 + 2048);                                   \
        av3 = *(const bf16x8*)(pA0 + 3072);                                   \
        bv0 = *(const bf16x8*)(pB0);                                          \
        bv1 = *(const bf16x8*)(pB0 + 1024);                                   \
        __builtin_amdgcn_s_setprio(1);                                        \
        acc[0][0] = MF(av0, bv0, acc[0][0]); acc[0][1] = MF(av0, bv1, acc[0][1]); \
        acc[1][0] = MF(av1, bv0, acc[1][0]); acc[1][1] = MF(av1, bv1, acc[1][1]); \
        acc[2][0] = MF(av2, bv0, acc[2][0]); acc[2][1] = MF(av2, bv1, acc[2][1]); \
        acc[3][0] = MF(av3, bv0, acc[3][0]); acc[3][1] = MF(av3, bv1, acc[3][1]); \
        __builtin_amdgcn_s_setprio(0);                                        \
        /* phase 1: kh0 x ni{2,3} (A held) */                                 \
        if (DOST) { STJ8(2, KT2, SB); STJ8(3, KT2, SB); }                     \
        bv0 = *(const bf16x8*)(pB0 + 2048);                                   \
        bv1 = *(const bf16x8*)(pB0 + 3072);                                   \
        __builtin_amdgcn_s_setprio(1);                                        \
        acc[0][2] = MF(av0, bv0, acc[0][2]); acc[0][3] = MF(av0, bv1, acc[0][3]); \
        acc[1][2] = MF(av1, bv0, acc[1][2]); acc[1][3] = MF(av1, bv1, acc[1][3]); \
        acc[2][2] = MF(av2, bv0, acc[2][2]); acc[2][3] = MF(av2, bv1, acc[2][3]); \
        acc[3][2] = MF(av3, bv0, acc[3][2]); acc[3][3] = MF(av3, bv1, acc[3][3]); \
        __builtin_amdgcn_s_setprio(0);                                        \
        /* phase 2: kh1 x ni{2,3} */                                          \
        if (DOST) { STJ8(4, KT2, SB); }                                       \
        av0 = *(const bf16x8*)(pA1);                                          \
        av1 = *(const bf16x8*)(pA1 + 1024);                                   \
        av2 = *(const bf16x8*)(pA1 + 2048);                                   \
        av3 = *(const bf16x8*)(pA1 + 3072);                                   \
        bv0 = *(const bf16x8*)(pB1 + 2048);                                   \
        bv1 = *(const bf16x8*)(pB1 + 3072);                                   \
        __builtin_amdgcn_s_setprio(1);                                        \
        acc[0][2] = MF(av0, bv0, acc[0][2]); acc[0][3] = MF(av0, bv1, acc[0][3]); \
        acc[1][2] = MF(av1, bv0, acc[1][2]); acc[1][3] = MF(av1, bv1, acc[1][3]); \
        acc[2][2] = MF(av2, bv0, acc[2][2]); acc[2][3] = MF(av2, bv1, acc[2][3]); \
        acc[3][2] = MF(av3, bv0, acc[3][2]); acc[3][3] = MF(av3, bv1, acc[3][3]); \
        __builtin_amdgcn_s_setprio(0);                                        \
        /* phase 3: kh1 x ni{0,1} (A held) */                                 \
        if (DOST) { STJ8(5, KT2, SB); }                                       \
        bv0 = *(const bf16x8*)(pB1);                                          \
        bv1 = *(const bf16x8*)(pB1 + 1024);                                   \
        __builtin_amdgcn_s_setprio(1);                                        \
        acc[0][0] = MF(av0, bv0, acc[0][0]); acc[0][1] = MF(av0, bv1, acc[0][1]); \
        acc[1][0] = MF(av1, bv0, acc[1][0]); acc[1][1] = MF(av1, bv1, acc[1][1]); \
        acc[2][0] = MF(av2, bv0, acc[2][0]); acc[2][1] = MF(av2, bv1, acc[2][1]); \
        acc[3][0] = MF(av3, bv0, acc[3][0]); acc[3][1] = MF(av3, bv1, acc[3][1]); \
        __builtin_amdgcn_s_setprio(0);                                        \
    }

    // prologue: tiles 0,1 staged (12 loads in flight/thread)
    STAGEALL8(0, 0);
    STAGEALL8(1, 1);
    // 16 K-tiles; buf = t%3; stage tile t+2 -> buf (t+2)%3
    for (int t = 0; t < 12; t += 3) {
        TILE8(6, 0, t + 2, 2, true);
        TILE8(6, 1, t + 3, 0, true);
        TILE8(6, 2, t + 4, 1, true);
    }
    TILE8(6, 0, 14, 2, true);    // t=12, stages tile 14
    TILE8(6, 1, 15, 0, true);    // t=13, stages tile 15
    TILE8(6, 2, 0, 0, false);    // t=14 (tile 15's 6 loads still in flight)
    TILE8(0, 0, 0, 0, false);    // t=15

#undef TILE8
#undef STAGEALL8
#undef STJ8

    // epilogue: C/D layout col=lane&15, row=(lane>>4)*4+reg; bias + ReLU
    const float* bp = bias_base + (size_t)c * bias_stride + n0 + wn * 64 + lr;
    #pragma unroll
    for (int ni = 0; ni < 4; ++ni) {
        const float bv = bp[ni * 16];
        const int col = n0 + wn * 64 + ni * 16 + lr;
        #pragma unroll
        for (int mi = 0; mi < 4; ++mi) {
            const int rb = m0 + wm * 64 + mi * 16 + lg * 4;
            #pragma unroll
            for (int q = 0; q < 4; ++q) {
                float v = acc[mi][ni][q] + bv;
                v = v > 0.f ? v : 0.f;
                Hout[(size_t)(rb + q) * HH + col] = f2bf(v);
            }
        }
    }
}

// ---------------------------------------------------------------------------
// L4 GEMM (N=256, final scatter): proven R5 structure, BM=BN=128, BK=32.
// ---------------------------------------------------------------------------
#define STAGE(b, kt)                            \
    {                                           \
        const int kb_ = (kt) * 32;              \
        GLDS16(gA0 + kb_, lA0 + (b) * 4096);    \
        GLDS16(gA1 + kb_, lA1 + (b) * 4096);    \
        GLDS16(gB0 + kb_, lB0 + (b) * 4096);    \
        GLDS16(gB1 + kb_, lB1 + (b) * 4096);    \
    }

#define COMPUTE(b)                                                        \
    {                                                                     \
        bf16x8 af[4], bfr[4];                                             \
        _Pragma("unroll")                                                 \
        for (int i = 0; i < 4; ++i) {                                     \
            af[i]  = *(const bf16x8*)(fA + (b) * 4096 + i * 16 * 32);     \
            bfr[i] = *(const bf16x8*)(fB + (b) * 4096 + i * 16 * 32);     \
        }                                                                 \
        __builtin_amdgcn_s_setprio(1);                                    \
        _Pragma("unroll")                                                 \
        for (int mi = 0; mi < 4; ++mi)                                    \
            _Pragma("unroll")                                             \
            for (int ni = 0; ni < 4; ++ni)                                \
                acc[mi][ni] = __builtin_amdgcn_mfma_f32_16x16x32_bf16(    \
                    af[mi], bfr[ni], acc[mi][ni], 0, 0, 0);               \
        __builtin_amdgcn_s_setprio(0);                                    \
    }

#define WAITV(N)                                                          \
    asm volatile("s_waitcnt vmcnt(" #N ")" ::: "memory");                 \
    __builtin_amdgcn_s_barrier();                                         \
    __builtin_amdgcn_sched_barrier(0);

__global__ __launch_bounds__(256, 3)
void gemm_final_kernel(const u16* __restrict__ Abase, const u16* __restrict__ Wbase,
                       size_t wclass_stride, const float* __restrict__ bias_base,
                       int bias_stride, const int* __restrict__ offsets,
                       const int* __restrict__ rowidx, float* __restrict__ Fout)
{
    __shared__ u16 sA[3 * 128 * 32];
    __shared__ u16 sB[3 * 128 * 32];
    const int tid = threadIdx.x;

    const int bid = blockIdx.x;
    const int wg = (bid & 7) * ((int)gridDim.x >> 3) + (bid >> 3);
    const int m0 = (wg >> 1) * 128;
    const int n0 = (wg & 1) * 128;
    if (m0 >= offsets[CC]) return;
    int c = 0;
    while (m0 >= offsets[c + 1]) ++c;

    const int srow = tid >> 2;
    const int kc8 = (tid & 3) * 8;
    const int sa0 = m0 + srow, sa1 = m0 + srow + 64;
    const u16* gA0 = Abase + (size_t)sa0 * 1024 + kc8;
    const u16* gA1 = Abase + (size_t)sa1 * 1024 + kc8;
    const u16* Wcl = Wbase + (size_t)c * wclass_stride;
    const u16* gB0 = Wcl + (size_t)(n0 + srow) * 1024 + kc8;
    const u16* gB1 = Wcl + (size_t)(n0 + srow + 64) * 1024 + kc8;
    u16* lA0 = sA + tid * 8;
    u16* lA1 = sA + 2048 + tid * 8;
    u16* lB0 = sB + tid * 8;
    u16* lB1 = sB + 2048 + tid * 8;

    const int lane = tid & 63, wv = tid >> 6;
    const int wm = (wv & 1) * 64, wn = (wv >> 1) * 64;
    const int lr = lane & 15, lg = lane >> 4;
    const u16* fA = sA + (wm + lr) * 32 + lg * 8;
    const u16* fB = sB + (wn + lr) * 32 + lg * 8;

    f32x4 acc[4][4];
    #pragma unroll
    for (int i = 0; i < 4; ++i)
        #pragma unroll
        for (int j = 0; j < 4; ++j)
            acc[i][j] = (f32x4){0.f, 0.f, 0.f, 0.f};

    STAGE(0, 0);
    STAGE(1, 1);
    for (int kt = 0; kt < 30; kt += 3) {
        WAITV(4);
        STAGE(2, kt + 2);
        COMPUTE(0);
        WAITV(4);
        STAGE(0, kt + 3);
        COMPUTE(1);
        WAITV(4);
        STAGE(1, kt + 4);
        COMPUTE(2);
    }
    WAITV(4);
    COMPUTE(0);
    WAITV(0);
    COMPUTE(1);

    const float* bp = bias_base + (size_t)c * bias_stride + n0 + wn + lr;
    #pragma unroll
    for (int ni = 0; ni < 4; ++ni) {
        const float bv = bp[ni * 16];
        const int col = n0 + wn + ni * 16 + lr;
        #pragma unroll
        for (int mi = 0; mi < 4; ++mi) {
            const int rb = m0 + wm + mi * 16 + lg * 4;
            #pragma unroll
            for (int q = 0; q < 4; ++q) {
                const float v = acc[mi][ni][q] + bv;
                const int orow = rowidx[rb + q];
                if (orow >= 0) Fout[(size_t)orow * OO + col] = v;
            }
        }
    }
}

// ---------------------------------------------------------------------------
extern "C" void kernel_launch(void* const* d_in, const int* in_sizes, int n_in,
                              void* d_out, int out_size, void* d_ws, size_t ws_size,
                              hipStream_t stream)
{
    const float* x  = (const float*)d_in[0];
    const float* Wc = (const float*)d_in[1];
    const float* bc = (const float*)d_in[2];
    const float* W1 = (const float*)d_in[3];
    const float* b1 = (const float*)d_in[4];
    const float* W2 = (const float*)d_in[5];
    const float* b2 = (const float*)d_in[6];
    const float* Wo = (const float*)d_in[7];
    const float* bo = (const float*)d_in[8];
    float* out    = (float*)d_out;                 // [B][O]
    float* logits = out + (size_t)BB * OO;         // [B][C]

    char* ws = (char*)d_ws;
    constexpr size_t PADMAX = BB + CC * 256;       // 18432 padded rows max
    constexpr int NLB = BB / 16;                   // 1024 logits blocks
    int* offsets   = (int*)(ws + 0);               // [9]
    int* hist      = (int*)(ws + 64);              // [NLB][8]
    int* bb        = (int*)(ws + 64 + NLB * 32);   // [NLB][8]
    int* class_idx = (int*)(ws + 64 + 2 * NLB * 32);
    int* rowidx    = (int*)((char*)class_idx + (size_t)BB * 4);
    u16* x_bf16    = (u16*)((char*)rowidx + PADMAX * 4);
    u16* hA  = x_bf16 + (size_t)BB * DD;
    u16* hB  = hA + PADMAX * HH;
    u16* W1T = hB + PADMAX * HH;                    // [C][H][D]
    u16* W2T = W1T + (size_t)CC * DD * HH;          // [C][2][H][H]
    u16* WoT = W2T + (size_t)CC * 2 * HH * HH;      // [C][O][H]

    hipMemsetAsync(rowidx, 0xFF, PADMAX * 4, stream);  // pad slots = -1

    transpose_bf16_kernel<<<dim3(32, 32, 8),  256, 0, stream>>>(W1, W1T, DD, HH);
    transpose_bf16_kernel<<<dim3(32, 32, 16), 256, 0, stream>>>(W2, W2T, HH, HH);
    transpose_bf16_kernel<<<dim3(8, 32, 8),   256, 0, stream>>>(Wo, WoT, HH, OO);

    logits_kernel<<<NLB, 256, 0, stream>>>(x, Wc, bc, logits, x_bf16, class_idx, hist);
    scan_kernel<<<1, 256, 0, stream>>>(hist, offsets, bb);
    scatter_kernel<<<BB / 256, 256, 0, stream>>>(class_idx, bb, rowidx);

    constexpr int MT2 = (int)(PADMAX / 256);  // 72 M-tiles (256-row)
    constexpr int MT4 = (int)(PADMAX / 128);  // 144 M-tiles (128-row, L4)
    gemm8p_kernel<true ><<<dim3(MT2 * 8), 512, 0, stream>>>(
        x_bf16, W1T, (size_t)DD * HH, b1, HH, offsets, rowidx, hA);
    gemm8p_kernel<false><<<dim3(MT2 * 8), 512, 0, stream>>>(
        hA, W2T, (size_t)2 * HH * HH, b2, 2 * HH, offsets, rowidx, hB);
    gemm8p_kernel<false><<<dim3(MT2 * 8), 512, 0, stream>>>(
        hB, W2T + (size_t)HH * HH, (size_t)2 * HH * HH, b2 + HH, 2 * HH, offsets, rowidx, hA);
    gemm_final_kernel<<<dim3(MT4 * 2), 256, 0, stream>>>(
        hA, WoT, (size_t)OO * HH, bo, OO, offsets, rowidx, out);
}